// Round 10
// baseline (306.613 us; speedup 1.0000x reference)
//
#include <hip/hip_runtime.h>
#include <hip/hip_fp16.h>
#include <math.h>

#define THREADS 256
#define BWIDTH 512          // nodes per bucket (pow2, shift 9)
#define BSHIFT 9
#define CHUNK 12500         // edges per partition block (no LDS stage needed)
#define G1ROWS 16
#define G2ROWS 16

// ---------------------------------------------------------------------------
// int64 detection + zero bucket counters
// ---------------------------------------------------------------------------
__global__ void init_kernel(const int* __restrict__ ei32, int* __restrict__ flag,
                            unsigned int* __restrict__ gcnt) {
    int t = threadIdx.x;
    gcnt[t] = 0u;
    if (t == 0) {
        int z = (ei32[1] == 0) + (ei32[3] == 0) + (ei32[5] == 0) + (ei32[7] == 0);
        *flag = (z == 4) ? 1 : 0;
    }
}

__device__ __forceinline__ int edge_at(const void* ei, int is64, size_t idx) {
    return is64 ? (int)((const long long*)ei)[idx] : ((const int*)ei)[idx];
}

// decode positive fp16 from low 15 bits of packed record
__device__ __forceinline__ float wdec(unsigned int v) {
    return __half2float(__ushort_as_half((unsigned short)(v & 0x7FFFu)));
}

// accumulate 8 fp16 dims (int4-packed) * w into acc[8]
__device__ __forceinline__ void acc8(float* acc, float w, int4 g) {
    float2 x0 = __half22float2(*(const __half2*)&g.x);
    float2 x1 = __half22float2(*(const __half2*)&g.y);
    float2 x2 = __half22float2(*(const __half2*)&g.z);
    float2 x3 = __half22float2(*(const __half2*)&g.w);
    acc[0] = fmaf(w, x0.x, acc[0]); acc[1] = fmaf(w, x0.y, acc[1]);
    acc[2] = fmaf(w, x1.x, acc[2]); acc[3] = fmaf(w, x1.y, acc[3]);
    acc[4] = fmaf(w, x2.x, acc[4]); acc[5] = fmaf(w, x2.y, acc[5]);
    acc[6] = fmaf(w, x3.x, acc[6]); acc[7] = fmaf(w, x3.y, acc[7]);
}

// ---------------------------------------------------------------------------
// P1: per-block bucket histogram; flush reserves each block's range per bucket
// ---------------------------------------------------------------------------
__global__ void p1_count_kernel(const void* __restrict__ ei, const int* __restrict__ flag,
                                unsigned int* __restrict__ gcnt, unsigned int* __restrict__ table,
                                int E, int B) {
    __shared__ unsigned int lcnt[256];
    int t = threadIdx.x, b = blockIdx.x;
    lcnt[t] = 0u;
    __syncthreads();
    int is64 = *flag;
    int base = b * CHUNK;
    int end = min(E, base + CHUNK);
    for (int e = base + t; e < end; e += THREADS) {
        int c = edge_at(ei, is64, (size_t)E + e);
        atomicAdd(&lcnt[c >> BSHIFT], 1u);
    }
    __syncthreads();
    if (t < B) table[(size_t)b * 256 + t] = atomicAdd(&gcnt[t], lcnt[t]);
}

// ---------------------------------------------------------------------------
// P2: exclusive scan of gcnt[0..B) -> bstart[0..B], bstart[B] = E
// ---------------------------------------------------------------------------
__global__ void p2_scan_kernel(const unsigned int* __restrict__ gcnt,
                               unsigned int* __restrict__ bstart, int B, int E) {
    int t = threadIdx.x;
    unsigned int v = (t < B) ? gcnt[t] : 0u;
    unsigned int incl = v;
    int lane = t & 63, wid = t >> 6;
#pragma unroll
    for (int off = 1; off < 64; off <<= 1) {
        unsigned int x = __shfl_up(incl, off);
        if (lane >= off) incl += x;
    }
    __shared__ unsigned int ws4[4];
    if (lane == 63) ws4[wid] = incl;
    __syncthreads();
    unsigned int wb = 0;
    for (int w = 0; w < wid; ++w) wb += ws4[w];
    unsigned int excl = wb + incl - v;
    if (t < B) bstart[t] = excl;
    if (t == 0) bstart[B] = (unsigned int)E;
}

// ---------------------------------------------------------------------------
// P3: DIRECT scatter. Each block's per-bucket range was reserved by p1; just
// bump an LDS cursor and write the 8B record. Writes cluster in ~128B windows
// per (block,bucket) -> L2 write-back stays clean. 1 LDS op/edge (was 7).
// ---------------------------------------------------------------------------
__global__ void p3_scatter_kernel(const void* __restrict__ ei, const float* __restrict__ ew,
                                  const int* __restrict__ flag,
                                  const unsigned int* __restrict__ bstart,
                                  const unsigned int* __restrict__ table,
                                  int2* __restrict__ out, int E, int B) {
    __shared__ unsigned int lcur[256];
    int t = threadIdx.x, b = blockIdx.x;
    lcur[t] = (t < B) ? (bstart[t] + table[(size_t)b * 256 + t]) : 0u;
    __syncthreads();
    int is64 = *flag;
    int base = b * CHUNK;
    int end = min(E, base + CHUNK);
    for (int e = base + t; e < end; e += THREADS) {
        int r = edge_at(ei, is64, (size_t)e);
        int c = edge_at(ei, is64, (size_t)E + e);
        int bin = c >> BSHIFT;
        unsigned int pos = atomicAdd(&lcur[bin], 1u);
        out[pos] = make_int2(r | ((c & (BWIDTH - 1)) << 17), __float_as_int(ew[e]));
    }
}

// ---------------------------------------------------------------------------
// P5: one block per bucket. LDS count + exact fp32 deg, scan -> colptr + dinv,
// node-sort within bucket -> packed csr u32 = (r<<15) | fp16bits(ew*dinv[c]).
// ---------------------------------------------------------------------------
__global__ void p5_bucket_kernel(const int2* __restrict__ bucketed,
                                 const unsigned int* __restrict__ bstart,
                                 float* __restrict__ dinv, int* __restrict__ colptr,
                                 unsigned int* __restrict__ csrp, int N, int E) {
    __shared__ unsigned int cnt[BWIDTH];
    __shared__ float deg[BWIDTH];       // degree, then reused as dinv
    __shared__ unsigned int cur[BWIDTH];
    __shared__ unsigned int ws4[4];

    int t = threadIdx.x, b = blockIdx.x;
    cnt[t] = 0u; cnt[t + 256] = 0u;
    deg[t] = 0.f; deg[t + 256] = 0.f;
    __syncthreads();
    unsigned int s = bstart[b], e2 = bstart[b + 1];
    for (unsigned int j = s + t; j < e2; j += THREADS) {
        int2 v = bucketed[j];
        unsigned int cl = ((unsigned int)v.x) >> 17;
        atomicAdd(&cnt[cl], 1u);
        atomicAdd(&deg[cl], __int_as_float(v.y));
    }
    __syncthreads();
    unsigned int a0 = cnt[2 * t], a1 = cnt[2 * t + 1];
    unsigned int sum = a0 + a1;
    unsigned int incl = sum;
    int lane = t & 63, wid = t >> 6;
#pragma unroll
    for (int off = 1; off < 64; off <<= 1) {
        unsigned int x = __shfl_up(incl, off);
        if (lane >= off) incl += x;
    }
    if (lane == 63) ws4[wid] = incl;
    __syncthreads();
    unsigned int wb = 0;
    for (int w = 0; w < wid; ++w) wb += ws4[w];
    unsigned int exclT = wb + incl - sum;
    unsigned int e0 = exclT, e1 = exclT + a0;
    int node0 = b << BSHIFT;
    int n0 = node0 + 2 * t, n1 = n0 + 1;
    float d0 = rsqrtf(deg[2 * t] + 1.0f);       // +1 self-loop
    float d1 = rsqrtf(deg[2 * t + 1] + 1.0f);
    if (n0 < N) { colptr[n0] = (int)(s + e0); dinv[n0] = d0; }
    if (n1 < N) { colptr[n1] = (int)(s + e1); dinv[n1] = d1; }
    deg[2 * t] = d0;
    deg[2 * t + 1] = d1;
    cur[2 * t] = s + e0;
    cur[2 * t + 1] = s + e1;
    __syncthreads();
    for (unsigned int j = s + t; j < e2; j += THREADS) {
        int2 v = bucketed[j];
        unsigned int cl = ((unsigned int)v.x) >> 17;
        unsigned int pos = atomicAdd(&cur[cl], 1u);
        float w = __int_as_float(v.y) * deg[cl];        // ew * dinv[c], > 0
        unsigned short hb = __half_as_ushort(__float2half_rn(w));
        csrp[pos] = (((unsigned int)v.x & 0x1FFFFu) << 15) | (unsigned int)(hb & 0x7FFFu);
    }
    if (b == 0 && t == 0) colptr[N] = E;
}

// ---------------------------------------------------------------------------
// GEMM1: Y[N][64] fp16 = dinv[row] * (X[N,64] @ W1[64,64]).
// Persistent blocks: W staged ONCE per block, grid-stride over 16-row tiles.
// ---------------------------------------------------------------------------
__global__ void gemm1_kernel(const float* __restrict__ X, const float* __restrict__ W,
                             const float* __restrict__ dinv, __half* __restrict__ Y,
                             int N, int tiles) {
    __shared__ float Wl[64 * 64];
    __shared__ float Xl[G1ROWS * 64];
    int tid = threadIdx.x;
    for (int i = tid; i < 64 * 64; i += 256) Wl[i] = W[i];
    int wid = tid >> 6, c = tid & 63;
    __syncthreads();
    for (int tile = blockIdx.x; tile < tiles; tile += gridDim.x) {
        int base = tile * G1ROWS;
        for (int i = tid; i < G1ROWS * 64; i += 256) {
            int rr = base + (i >> 6);
            Xl[i] = (rr < N) ? X[(size_t)rr * 64 + (i & 63)] : 0.f;
        }
        __syncthreads();
#pragma unroll
        for (int rg = 0; rg < G1ROWS / 4; ++rg) {
            int r = rg * 4 + wid;
            int row = base + r;
            if (row < N) {
                float acc = 0.f;
#pragma unroll
                for (int k = 0; k < 64; ++k) acc = fmaf(Xl[r * 64 + k], Wl[k * 64 + c], acc);
                Y[(size_t)row * 64 + c] = __float2half(acc * dinv[row]);
            }
        }
        __syncthreads();
    }
}

// ---------------------------------------------------------------------------
// GEMM2: Y[N][32] fp16 = dinv[row] * (H[N,64] @ W2[64,32]). Persistent blocks.
// ---------------------------------------------------------------------------
__global__ void gemm2_kernel(const __half* __restrict__ H, const float* __restrict__ W,
                             const float* __restrict__ dinv, __half* __restrict__ Y,
                             int N, int tiles) {
    __shared__ float Wl[64 * 32];
    __shared__ float Xl[G2ROWS * 64];
    int tid = threadIdx.x;
    for (int i = tid; i < 64 * 32; i += 256) Wl[i] = W[i];
    int rg0 = tid >> 5, c = tid & 31;
    __syncthreads();
    for (int tile = blockIdx.x; tile < tiles; tile += gridDim.x) {
        int base = tile * G2ROWS;
        for (int i = tid; i < G2ROWS * 32; i += 256) {       // half2 units
            int rr = base + (i >> 5);
            int kk = (i & 31) << 1;
            float2 f = make_float2(0.f, 0.f);
            if (rr < N) f = __half22float2(*(const __half2*)(H + (size_t)rr * 64 + kk));
            Xl[(i >> 5) * 64 + kk] = f.x;
            Xl[(i >> 5) * 64 + kk + 1] = f.y;
        }
        __syncthreads();
#pragma unroll
        for (int rg = 0; rg < G2ROWS / 8; ++rg) {
            int r = rg * 8 + rg0;
            int row = base + r;
            if (row < N) {
                float acc = 0.f;
#pragma unroll
                for (int k = 0; k < 64; ++k) acc = fmaf(Xl[r * 64 + k], Wl[k * 32 + c], acc);
                Y[(size_t)row * 32 + c] = __float2half(acc * dinv[row]);
            }
        }
        __syncthreads();
    }
}

// ---------------------------------------------------------------------------
// agg1: wave per node; lane = (eo in [0,8), dq in [0,8)). Each lane gathers
// int4 = 8 fp16 dims -> ONE gather inst covers 8 full rows (1 KB).
// ---------------------------------------------------------------------------
__global__ void agg1_kernel(const __half* __restrict__ X1, const int* __restrict__ colptr,
                            const unsigned int* __restrict__ csrp,
                            const float* __restrict__ dinv, const float* __restrict__ bias,
                            __half* __restrict__ H, int N) {
    int tid = threadIdx.x;
    int node = blockIdx.x * 4 + (tid >> 6);
    if (node >= N) return;
    int lane = tid & 63;
    int eo = lane >> 3;
    int dq = lane & 7;
    int s = colptr[node], e = colptr[node + 1];
    float acc[8] = {0.f, 0.f, 0.f, 0.f, 0.f, 0.f, 0.f, 0.f};
    int j = s;
    while (j + 16 <= e) {
        unsigned int v0 = __builtin_nontemporal_load(&csrp[j + eo]);
        unsigned int v1 = __builtin_nontemporal_load(&csrp[j + 8 + eo]);
        int r0 = (int)(v0 >> 15), r1 = (int)(v1 >> 15);
        int4 g0 = *(const int4*)(X1 + ((size_t)r0 << 6) + (dq << 3));
        int4 g1 = *(const int4*)(X1 + ((size_t)r1 << 6) + (dq << 3));
        acc8(acc, wdec(v0), g0);
        acc8(acc, wdec(v1), g1);
        j += 16;
    }
    for (; j < e; j += 8) {
        int jj = j + eo;
        unsigned int v = (jj < e) ? csrp[jj] : 0u;
        float w = (jj < e) ? wdec(v) : 0.f;
        int r = (int)(v >> 15);
        int4 g = *(const int4*)(X1 + ((size_t)r << 6) + (dq << 3));
        acc8(acc, w, g);
    }
#pragma unroll
    for (int k = 0; k < 8; ++k) {
        acc[k] += __shfl_xor(acc[k], 8);
        acc[k] += __shfl_xor(acc[k], 16);
        acc[k] += __shfl_xor(acc[k], 32);
    }
    if (eo == 0) {
        float di = dinv[node];
        int4 gs = *(const int4*)(X1 + ((size_t)node << 6) + (dq << 3));
        float4 b0 = *(const float4*)(bias + dq * 8);
        float4 b1 = *(const float4*)(bias + dq * 8 + 4);
        float2 x0 = __half22float2(*(const __half2*)&gs.x);
        float2 x1 = __half22float2(*(const __half2*)&gs.y);
        float2 x2 = __half22float2(*(const __half2*)&gs.z);
        float2 x3 = __half22float2(*(const __half2*)&gs.w);
        float a0 = fmaxf(b0.x + fmaf(di, x0.x, acc[0]), 0.f);
        float a1 = fmaxf(b0.y + fmaf(di, x0.y, acc[1]), 0.f);
        float a2 = fmaxf(b0.z + fmaf(di, x1.x, acc[2]), 0.f);
        float a3 = fmaxf(b0.w + fmaf(di, x1.y, acc[3]), 0.f);
        float a4 = fmaxf(b1.x + fmaf(di, x2.x, acc[4]), 0.f);
        float a5 = fmaxf(b1.y + fmaf(di, x2.y, acc[5]), 0.f);
        float a6 = fmaxf(b1.z + fmaf(di, x3.x, acc[6]), 0.f);
        float a7 = fmaxf(b1.w + fmaf(di, x3.y, acc[7]), 0.f);
        int4 o;
        *(__half2*)&o.x = __floats2half2_rn(a0, a1);
        *(__half2*)&o.y = __floats2half2_rn(a2, a3);
        *(__half2*)&o.z = __floats2half2_rn(a4, a5);
        *(__half2*)&o.w = __floats2half2_rn(a6, a7);
        *(int4*)(H + ((size_t)node << 6) + (dq << 3)) = o;
    }
}

// ---------------------------------------------------------------------------
// agg2: wave per node; lane = (eo in [0,16), dq in [0,4)). int4 gather ->
// ONE inst covers 16 rows. Reduce across eo, in-wave L2-normalize, fp32 out.
// ---------------------------------------------------------------------------
__global__ void agg2_kernel(const __half* __restrict__ X2, const int* __restrict__ colptr,
                            const unsigned int* __restrict__ csrp,
                            const float* __restrict__ dinv, const float* __restrict__ bias,
                            float* __restrict__ out, int N) {
    int tid = threadIdx.x;
    int node = blockIdx.x * 4 + (tid >> 6);
    if (node >= N) return;
    int lane = tid & 63;
    int eo = lane >> 2;
    int dq = lane & 3;
    int s = colptr[node], e = colptr[node + 1];
    float acc[8] = {0.f, 0.f, 0.f, 0.f, 0.f, 0.f, 0.f, 0.f};
    int j = s;
    while (j + 16 <= e) {
        unsigned int v = __builtin_nontemporal_load(&csrp[j + eo]);
        int r = (int)(v >> 15);
        int4 g = *(const int4*)(X2 + ((size_t)r << 5) + (dq << 3));
        acc8(acc, wdec(v), g);
        j += 16;
    }
    if (j < e) {
        int jj = j + eo;
        unsigned int v = (jj < e) ? csrp[jj] : 0u;
        float w = (jj < e) ? wdec(v) : 0.f;
        int r = (int)(v >> 15);
        int4 g = *(const int4*)(X2 + ((size_t)r << 5) + (dq << 3));
        acc8(acc, w, g);
    }
#pragma unroll
    for (int k = 0; k < 8; ++k) {
        acc[k] += __shfl_xor(acc[k], 4);
        acc[k] += __shfl_xor(acc[k], 8);
        acc[k] += __shfl_xor(acc[k], 16);
        acc[k] += __shfl_xor(acc[k], 32);
    }
    float a[8];
    float ss = 0.f;
    {
        float di = dinv[node];
        int4 gs = *(const int4*)(X2 + ((size_t)node << 5) + (dq << 3));
        float4 b0 = *(const float4*)(bias + dq * 8);
        float4 b1 = *(const float4*)(bias + dq * 8 + 4);
        float2 x0 = __half22float2(*(const __half2*)&gs.x);
        float2 x1 = __half22float2(*(const __half2*)&gs.y);
        float2 x2 = __half22float2(*(const __half2*)&gs.z);
        float2 x3 = __half22float2(*(const __half2*)&gs.w);
        a[0] = b0.x + fmaf(di, x0.x, acc[0]);
        a[1] = b0.y + fmaf(di, x0.y, acc[1]);
        a[2] = b0.z + fmaf(di, x1.x, acc[2]);
        a[3] = b0.w + fmaf(di, x1.y, acc[3]);
        a[4] = b1.x + fmaf(di, x2.x, acc[4]);
        a[5] = b1.y + fmaf(di, x2.y, acc[5]);
        a[6] = b1.z + fmaf(di, x3.x, acc[6]);
        a[7] = b1.w + fmaf(di, x3.y, acc[7]);
#pragma unroll
        for (int k = 0; k < 8; ++k) ss = fmaf(a[k], a[k], ss);
    }
    ss += __shfl_xor(ss, 1);
    ss += __shfl_xor(ss, 2);
    float inv = 1.f / fmaxf(sqrtf(ss), 1e-12f);
    if (eo == 0) {
        float4 o0 = make_float4(a[0] * inv, a[1] * inv, a[2] * inv, a[3] * inv);
        float4 o1 = make_float4(a[4] * inv, a[5] * inv, a[6] * inv, a[7] * inv);
        *(float4*)(out + ((size_t)node << 5) + (dq << 3)) = o0;
        *(float4*)(out + ((size_t)node << 5) + (dq << 3) + 4) = o1;
    }
}

extern "C" void kernel_launch(void* const* d_in, const int* in_sizes, int n_in,
                              void* d_out, int out_size, void* d_ws, size_t ws_size,
                              hipStream_t stream) {
    const void* ei = d_in[0];
    const float* ew = (const float*)d_in[1];
    const float* emb = (const float*)d_in[2];
    const float* W1 = (const float*)d_in[3];
    const float* b1 = (const float*)d_in[4];
    const float* W2 = (const float*)d_in[5];
    const float* b2 = (const float*)d_in[6];
    float* outp = (float*)d_out;

    int E = in_sizes[0] / 2;
    int N = in_sizes[2] / 64;
    int B = (N + BWIDTH - 1) >> BSHIFT;
    int GP = (E + CHUNK - 1) / CHUNK;

    char* p = (char*)d_ws;
    auto alloc = [&](size_t bytes) {
        void* q = (void*)p;
        p += (bytes + 255) & ~(size_t)255;
        return q;
    };
    unsigned int* gcnt   = (unsigned int*)alloc(256 * 4);
    unsigned int* bstart = (unsigned int*)alloc(257 * 4);
    int*          flag   = (int*)alloc(256);
    unsigned int* table  = (unsigned int*)alloc((size_t)GP * 256 * 4);
    int2*   bucketed = (int2*)alloc((size_t)E * 8);
    unsigned int* csrp = (unsigned int*)alloc(((size_t)E + 64) * 4);
    float*  dinv     = (float*)alloc((size_t)N * 4);
    int*    colptr   = (int*)alloc(((size_t)N + 1) * 4);
    __half* X1h      = (__half*)alloc((size_t)N * 64 * 2);   // reused as X2h [N][32]
    __half* H        = (__half*)alloc((size_t)N * 64 * 2);
    __half* X2h      = X1h;

    int tiles1 = (N + G1ROWS - 1) / G1ROWS;
    int tiles2 = (N + G2ROWS - 1) / G2ROWS;

    init_kernel<<<1, 256, 0, stream>>>((const int*)ei, flag, gcnt);
    p1_count_kernel<<<GP, THREADS, 0, stream>>>(ei, flag, gcnt, table, E, B);
    p2_scan_kernel<<<1, 256, 0, stream>>>(gcnt, bstart, B, E);
    p3_scatter_kernel<<<GP, THREADS, 0, stream>>>(ei, ew, flag, bstart, table,
                                                  bucketed, E, B);
    p5_bucket_kernel<<<B, THREADS, 0, stream>>>(bucketed, bstart, dinv, colptr, csrp, N, E);
    gemm1_kernel<<<1024, THREADS, 0, stream>>>(emb, W1, dinv, X1h, N, tiles1);
    agg1_kernel<<<(N + 3) / 4, THREADS, 0, stream>>>(X1h, colptr, csrp, dinv, b1, H, N);
    gemm2_kernel<<<1024, THREADS, 0, stream>>>(H, W2, dinv, X2h, N, tiles2);
    agg2_kernel<<<(N + 3) / 4, THREADS, 0, stream>>>(X2h, colptr, csrp, dinv, b2, outp, N);
}

// Round 11
// 287.860 us; speedup vs baseline: 1.0651x; 1.0651x over previous
//
#include <hip/hip_runtime.h>
#include <hip/hip_fp16.h>
#include <math.h>

#define THREADS 256
#define P5THREADS 512
#define BWIDTH 512          // nodes per bucket (pow2, shift 9)
#define BSHIFT 9
#define CHUNK 3125          // edges per partition block (<= 3136 LDS stage)
#define G1ROWS 16
#define G2ROWS 16

// ---------------------------------------------------------------------------
// int64 detection + zero bucket counters
// ---------------------------------------------------------------------------
__global__ void init_kernel(const int* __restrict__ ei32, int* __restrict__ flag,
                            unsigned int* __restrict__ gcnt) {
    int t = threadIdx.x;
    gcnt[t] = 0u;
    if (t == 0) {
        int z = (ei32[1] == 0) + (ei32[3] == 0) + (ei32[5] == 0) + (ei32[7] == 0);
        *flag = (z == 4) ? 1 : 0;
    }
}

__device__ __forceinline__ int edge_at(const void* ei, int is64, size_t idx) {
    return is64 ? (int)((const long long*)ei)[idx] : ((const int*)ei)[idx];
}

// decode positive fp16 from low 15 bits of packed record
__device__ __forceinline__ float wdec(unsigned int v) {
    return __half2float(__ushort_as_half((unsigned short)(v & 0x7FFFu)));
}

// accumulate 8 fp16 dims (int4-packed) * w into acc[8]
__device__ __forceinline__ void acc8(float* acc, float w, int4 g) {
    float2 x0 = __half22float2(*(const __half2*)&g.x);
    float2 x1 = __half22float2(*(const __half2*)&g.y);
    float2 x2 = __half22float2(*(const __half2*)&g.z);
    float2 x3 = __half22float2(*(const __half2*)&g.w);
    acc[0] = fmaf(w, x0.x, acc[0]); acc[1] = fmaf(w, x0.y, acc[1]);
    acc[2] = fmaf(w, x1.x, acc[2]); acc[3] = fmaf(w, x1.y, acc[3]);
    acc[4] = fmaf(w, x2.x, acc[4]); acc[5] = fmaf(w, x2.y, acc[5]);
    acc[6] = fmaf(w, x3.x, acc[6]); acc[7] = fmaf(w, x3.y, acc[7]);
}

// ---------------------------------------------------------------------------
// P1: per-block bucket histogram; flush reserves each block's range per bucket
// ---------------------------------------------------------------------------
__global__ void p1_count_kernel(const void* __restrict__ ei, const int* __restrict__ flag,
                                unsigned int* __restrict__ gcnt, unsigned int* __restrict__ table,
                                int E, int B) {
    __shared__ unsigned int lcnt[256];
    int t = threadIdx.x, b = blockIdx.x;
    lcnt[t] = 0u;
    __syncthreads();
    int is64 = *flag;
    int base = b * CHUNK;
    int end = min(E, base + CHUNK);
    for (int e = base + t; e < end; e += THREADS) {
        int c = edge_at(ei, is64, (size_t)E + e);
        atomicAdd(&lcnt[c >> BSHIFT], 1u);
    }
    __syncthreads();
    if (t < B) table[(size_t)b * 256 + t] = atomicAdd(&gcnt[t], lcnt[t]);
}

// ---------------------------------------------------------------------------
// P2: exclusive scan of gcnt[0..B) -> bstart[0..B], bstart[B] = E
// ---------------------------------------------------------------------------
__global__ void p2_scan_kernel(const unsigned int* __restrict__ gcnt,
                               unsigned int* __restrict__ bstart, int B, int E) {
    int t = threadIdx.x;
    unsigned int v = (t < B) ? gcnt[t] : 0u;
    unsigned int incl = v;
    int lane = t & 63, wid = t >> 6;
#pragma unroll
    for (int off = 1; off < 64; off <<= 1) {
        unsigned int x = __shfl_up(incl, off);
        if (lane >= off) incl += x;
    }
    __shared__ unsigned int ws4[4];
    if (lane == 63) ws4[wid] = incl;
    __syncthreads();
    unsigned int wb = 0;
    for (int w = 0; w < wid; ++w) wb += ws4[w];
    unsigned int excl = wb + incl - v;
    if (t < B) bstart[t] = excl;
    if (t == 0) bstart[B] = (unsigned int)E;
}

// ---------------------------------------------------------------------------
// P3: stage CHUNK edges in LDS, counting-sort by bucket, write coalesced
// bursts into block-reserved contiguous ranges. record = (r | c_local<<17, ew)
// (R10 lesson: the LDS permutation buys coalesced global writes — keep it.)
// ---------------------------------------------------------------------------
__global__ void p3_scatter_kernel(const void* __restrict__ ei, const float* __restrict__ ew,
                                  const int* __restrict__ flag,
                                  const unsigned int* __restrict__ bstart,
                                  const unsigned int* __restrict__ table,
                                  int2* __restrict__ out, int E, int B) {
    __shared__ int2 stage[CHUNK];
    __shared__ unsigned char lbin[CHUNK];
    __shared__ unsigned short perm[CHUNK];
    __shared__ unsigned int lcnt[256];
    __shared__ unsigned int lcur[256];
    __shared__ int shiftb[256];
    __shared__ unsigned int ws4[4];

    int t = threadIdx.x, b = blockIdx.x;
    lcnt[t] = 0u;
    __syncthreads();
    int is64 = *flag;
    int base = b * CHUNK;
    int end = min(E, base + CHUNK);
    int n = end - base;
    for (int i = t; i < n; i += THREADS) {
        int e = base + i;
        int r = edge_at(ei, is64, (size_t)e);
        int c = edge_at(ei, is64, (size_t)E + e);
        int bin = c >> BSHIFT;
        stage[i] = make_int2(r | ((c & (BWIDTH - 1)) << 17), __float_as_int(ew[e]));
        lbin[i] = (unsigned char)bin;
        atomicAdd(&lcnt[bin], 1u);
    }
    __syncthreads();
    unsigned int v = lcnt[t];
    unsigned int incl = v;
    int lane = t & 63, wid = t >> 6;
#pragma unroll
    for (int off = 1; off < 64; off <<= 1) {
        unsigned int x = __shfl_up(incl, off);
        if (lane >= off) incl += x;
    }
    if (lane == 63) ws4[wid] = incl;
    __syncthreads();
    unsigned int wb = 0;
    for (int w = 0; w < wid; ++w) wb += ws4[w];
    unsigned int excl = wb + incl - v;
    lcur[t] = excl;
    shiftb[t] = (t < B) ? ((int)(bstart[t] + table[(size_t)b * 256 + t]) - (int)excl) : 0;
    __syncthreads();
    for (int i = t; i < n; i += THREADS) {
        unsigned int pos = atomicAdd(&lcur[lbin[i]], 1u);
        perm[pos] = (unsigned short)i;
    }
    __syncthreads();
    for (int k = t; k < n; k += THREADS) {
        int i = perm[k];
        int bin = lbin[i];
        out[(size_t)(shiftb[bin] + k)] = stage[i];
    }
}

// ---------------------------------------------------------------------------
// P5: one block per bucket, 512 threads (8 waves -> fills the CU; was the
// only under-occupied kernel in the chain). Thread t owns bin t. Two passes:
// count + exact fp32 deg, scan -> colptr + dinv, then node-sort -> packed
// csr u32 = (r<<15) | fp16bits(ew*dinv[c]).
// ---------------------------------------------------------------------------
__global__ void p5_bucket_kernel(const int2* __restrict__ bucketed,
                                 const unsigned int* __restrict__ bstart,
                                 float* __restrict__ dinv, int* __restrict__ colptr,
                                 unsigned int* __restrict__ csrp, int N, int E) {
    __shared__ unsigned int cnt[BWIDTH];
    __shared__ float deg[BWIDTH];       // degree, then reused as dinv
    __shared__ unsigned int cur[BWIDTH];
    __shared__ unsigned int ws8[8];

    int t = threadIdx.x, b = blockIdx.x;
    cnt[t] = 0u;
    deg[t] = 0.f;
    __syncthreads();
    unsigned int s = bstart[b], e2 = bstart[b + 1];
    for (unsigned int j = s + t; j < e2; j += P5THREADS) {
        int2 v = bucketed[j];
        unsigned int cl = ((unsigned int)v.x) >> 17;
        atomicAdd(&cnt[cl], 1u);
        atomicAdd(&deg[cl], __int_as_float(v.y));
    }
    __syncthreads();
    // block-wide exclusive scan, 1 bin per thread (512 bins, 8 waves)
    unsigned int v = cnt[t];
    unsigned int incl = v;
    int lane = t & 63, wid = t >> 6;
#pragma unroll
    for (int off = 1; off < 64; off <<= 1) {
        unsigned int x = __shfl_up(incl, off);
        if (lane >= off) incl += x;
    }
    if (lane == 63) ws8[wid] = incl;
    __syncthreads();
    unsigned int wb = 0;
    for (int w = 0; w < wid; ++w) wb += ws8[w];
    unsigned int excl = wb + incl - v;
    int node = (b << BSHIFT) + t;
    float d = rsqrtf(deg[t] + 1.0f);        // +1 self-loop
    if (node < N) { colptr[node] = (int)(s + excl); dinv[node] = d; }
    deg[t] = d;
    cur[t] = s + excl;
    __syncthreads();
    for (unsigned int j = s + t; j < e2; j += P5THREADS) {
        int2 v2 = bucketed[j];
        unsigned int cl = ((unsigned int)v2.x) >> 17;
        unsigned int pos = atomicAdd(&cur[cl], 1u);
        float w = __int_as_float(v2.y) * deg[cl];       // ew * dinv[c], > 0
        unsigned short hb = __half_as_ushort(__float2half_rn(w));
        csrp[pos] = (((unsigned int)v2.x & 0x1FFFFu) << 15) | (unsigned int)(hb & 0x7FFFu);
    }
    if (b == 0 && t == 0) colptr[N] = E;
}

// ---------------------------------------------------------------------------
// GEMM1: Y[N][64] fp16 = dinv[row] * (X[N,64] @ W1[64,64]).
// Persistent blocks: W staged ONCE per block, grid-stride over 16-row tiles.
// ---------------------------------------------------------------------------
__global__ void gemm1_kernel(const float* __restrict__ X, const float* __restrict__ W,
                             const float* __restrict__ dinv, __half* __restrict__ Y,
                             int N, int tiles) {
    __shared__ float Wl[64 * 64];
    __shared__ float Xl[G1ROWS * 64];
    int tid = threadIdx.x;
    for (int i = tid; i < 64 * 64; i += 256) Wl[i] = W[i];
    int wid = tid >> 6, c = tid & 63;
    __syncthreads();
    for (int tile = blockIdx.x; tile < tiles; tile += gridDim.x) {
        int base = tile * G1ROWS;
        for (int i = tid; i < G1ROWS * 64; i += 256) {
            int rr = base + (i >> 6);
            Xl[i] = (rr < N) ? X[(size_t)rr * 64 + (i & 63)] : 0.f;
        }
        __syncthreads();
#pragma unroll
        for (int rg = 0; rg < G1ROWS / 4; ++rg) {
            int r = rg * 4 + wid;
            int row = base + r;
            if (row < N) {
                float acc = 0.f;
#pragma unroll
                for (int k = 0; k < 64; ++k) acc = fmaf(Xl[r * 64 + k], Wl[k * 64 + c], acc);
                Y[(size_t)row * 64 + c] = __float2half(acc * dinv[row]);
            }
        }
        __syncthreads();
    }
}

// ---------------------------------------------------------------------------
// GEMM2: Y[N][32] fp16 = dinv[row] * (H[N,64] @ W2[64,32]). Persistent blocks.
// ---------------------------------------------------------------------------
__global__ void gemm2_kernel(const __half* __restrict__ H, const float* __restrict__ W,
                             const float* __restrict__ dinv, __half* __restrict__ Y,
                             int N, int tiles) {
    __shared__ float Wl[64 * 32];
    __shared__ float Xl[G2ROWS * 64];
    int tid = threadIdx.x;
    for (int i = tid; i < 64 * 32; i += 256) Wl[i] = W[i];
    int rg0 = tid >> 5, c = tid & 31;
    __syncthreads();
    for (int tile = blockIdx.x; tile < tiles; tile += gridDim.x) {
        int base = tile * G2ROWS;
        for (int i = tid; i < G2ROWS * 32; i += 256) {       // half2 units
            int rr = base + (i >> 5);
            int kk = (i & 31) << 1;
            float2 f = make_float2(0.f, 0.f);
            if (rr < N) f = __half22float2(*(const __half2*)(H + (size_t)rr * 64 + kk));
            Xl[(i >> 5) * 64 + kk] = f.x;
            Xl[(i >> 5) * 64 + kk + 1] = f.y;
        }
        __syncthreads();
#pragma unroll
        for (int rg = 0; rg < G2ROWS / 8; ++rg) {
            int r = rg * 8 + rg0;
            int row = base + r;
            if (row < N) {
                float acc = 0.f;
#pragma unroll
                for (int k = 0; k < 64; ++k) acc = fmaf(Xl[r * 64 + k], Wl[k * 32 + c], acc);
                Y[(size_t)row * 32 + c] = __float2half(acc * dinv[row]);
            }
        }
        __syncthreads();
    }
}

// ---------------------------------------------------------------------------
// agg1: wave per node; lane = (eo in [0,8), dq in [0,8)). Each lane gathers
// int4 = 8 fp16 dims -> ONE gather inst covers 8 full rows (1 KB).
// ---------------------------------------------------------------------------
__global__ void agg1_kernel(const __half* __restrict__ X1, const int* __restrict__ colptr,
                            const unsigned int* __restrict__ csrp,
                            const float* __restrict__ dinv, const float* __restrict__ bias,
                            __half* __restrict__ H, int N) {
    int tid = threadIdx.x;
    int node = blockIdx.x * 4 + (tid >> 6);
    if (node >= N) return;
    int lane = tid & 63;
    int eo = lane >> 3;
    int dq = lane & 7;
    int s = colptr[node], e = colptr[node + 1];
    float acc[8] = {0.f, 0.f, 0.f, 0.f, 0.f, 0.f, 0.f, 0.f};
    int j = s;
    while (j + 16 <= e) {
        unsigned int v0 = __builtin_nontemporal_load(&csrp[j + eo]);
        unsigned int v1 = __builtin_nontemporal_load(&csrp[j + 8 + eo]);
        int r0 = (int)(v0 >> 15), r1 = (int)(v1 >> 15);
        int4 g0 = *(const int4*)(X1 + ((size_t)r0 << 6) + (dq << 3));
        int4 g1 = *(const int4*)(X1 + ((size_t)r1 << 6) + (dq << 3));
        acc8(acc, wdec(v0), g0);
        acc8(acc, wdec(v1), g1);
        j += 16;
    }
    for (; j < e; j += 8) {
        int jj = j + eo;
        unsigned int v = (jj < e) ? csrp[jj] : 0u;
        float w = (jj < e) ? wdec(v) : 0.f;
        int r = (int)(v >> 15);
        int4 g = *(const int4*)(X1 + ((size_t)r << 6) + (dq << 3));
        acc8(acc, w, g);
    }
#pragma unroll
    for (int k = 0; k < 8; ++k) {
        acc[k] += __shfl_xor(acc[k], 8);
        acc[k] += __shfl_xor(acc[k], 16);
        acc[k] += __shfl_xor(acc[k], 32);
    }
    if (eo == 0) {
        float di = dinv[node];
        int4 gs = *(const int4*)(X1 + ((size_t)node << 6) + (dq << 3));
        float4 b0 = *(const float4*)(bias + dq * 8);
        float4 b1 = *(const float4*)(bias + dq * 8 + 4);
        float2 x0 = __half22float2(*(const __half2*)&gs.x);
        float2 x1 = __half22float2(*(const __half2*)&gs.y);
        float2 x2 = __half22float2(*(const __half2*)&gs.z);
        float2 x3 = __half22float2(*(const __half2*)&gs.w);
        float a0 = fmaxf(b0.x + fmaf(di, x0.x, acc[0]), 0.f);
        float a1 = fmaxf(b0.y + fmaf(di, x0.y, acc[1]), 0.f);
        float a2 = fmaxf(b0.z + fmaf(di, x1.x, acc[2]), 0.f);
        float a3 = fmaxf(b0.w + fmaf(di, x1.y, acc[3]), 0.f);
        float a4 = fmaxf(b1.x + fmaf(di, x2.x, acc[4]), 0.f);
        float a5 = fmaxf(b1.y + fmaf(di, x2.y, acc[5]), 0.f);
        float a6 = fmaxf(b1.z + fmaf(di, x3.x, acc[6]), 0.f);
        float a7 = fmaxf(b1.w + fmaf(di, x3.y, acc[7]), 0.f);
        int4 o;
        *(__half2*)&o.x = __floats2half2_rn(a0, a1);
        *(__half2*)&o.y = __floats2half2_rn(a2, a3);
        *(__half2*)&o.z = __floats2half2_rn(a4, a5);
        *(__half2*)&o.w = __floats2half2_rn(a6, a7);
        *(int4*)(H + ((size_t)node << 6) + (dq << 3)) = o;
    }
}

// ---------------------------------------------------------------------------
// agg2: wave per node; lane = (eo in [0,16), dq in [0,4)). int4 gather ->
// ONE inst covers 16 rows. Reduce across eo, in-wave L2-normalize, fp32 out.
// ---------------------------------------------------------------------------
__global__ void agg2_kernel(const __half* __restrict__ X2, const int* __restrict__ colptr,
                            const unsigned int* __restrict__ csrp,
                            const float* __restrict__ dinv, const float* __restrict__ bias,
                            float* __restrict__ out, int N) {
    int tid = threadIdx.x;
    int node = blockIdx.x * 4 + (tid >> 6);
    if (node >= N) return;
    int lane = tid & 63;
    int eo = lane >> 2;
    int dq = lane & 3;
    int s = colptr[node], e = colptr[node + 1];
    float acc[8] = {0.f, 0.f, 0.f, 0.f, 0.f, 0.f, 0.f, 0.f};
    int j = s;
    while (j + 16 <= e) {
        unsigned int v = __builtin_nontemporal_load(&csrp[j + eo]);
        int r = (int)(v >> 15);
        int4 g = *(const int4*)(X2 + ((size_t)r << 5) + (dq << 3));
        acc8(acc, wdec(v), g);
        j += 16;
    }
    if (j < e) {
        int jj = j + eo;
        unsigned int v = (jj < e) ? csrp[jj] : 0u;
        float w = (jj < e) ? wdec(v) : 0.f;
        int r = (int)(v >> 15);
        int4 g = *(const int4*)(X2 + ((size_t)r << 5) + (dq << 3));
        acc8(acc, w, g);
    }
#pragma unroll
    for (int k = 0; k < 8; ++k) {
        acc[k] += __shfl_xor(acc[k], 4);
        acc[k] += __shfl_xor(acc[k], 8);
        acc[k] += __shfl_xor(acc[k], 16);
        acc[k] += __shfl_xor(acc[k], 32);
    }
    float a[8];
    float ss = 0.f;
    {
        float di = dinv[node];
        int4 gs = *(const int4*)(X2 + ((size_t)node << 5) + (dq << 3));
        float4 b0 = *(const float4*)(bias + dq * 8);
        float4 b1 = *(const float4*)(bias + dq * 8 + 4);
        float2 x0 = __half22float2(*(const __half2*)&gs.x);
        float2 x1 = __half22float2(*(const __half2*)&gs.y);
        float2 x2 = __half22float2(*(const __half2*)&gs.z);
        float2 x3 = __half22float2(*(const __half2*)&gs.w);
        a[0] = b0.x + fmaf(di, x0.x, acc[0]);
        a[1] = b0.y + fmaf(di, x0.y, acc[1]);
        a[2] = b0.z + fmaf(di, x1.x, acc[2]);
        a[3] = b0.w + fmaf(di, x1.y, acc[3]);
        a[4] = b1.x + fmaf(di, x2.x, acc[4]);
        a[5] = b1.y + fmaf(di, x2.y, acc[5]);
        a[6] = b1.z + fmaf(di, x3.x, acc[6]);
        a[7] = b1.w + fmaf(di, x3.y, acc[7]);
#pragma unroll
        for (int k = 0; k < 8; ++k) ss = fmaf(a[k], a[k], ss);
    }
    ss += __shfl_xor(ss, 1);
    ss += __shfl_xor(ss, 2);
    float inv = 1.f / fmaxf(sqrtf(ss), 1e-12f);
    if (eo == 0) {
        float4 o0 = make_float4(a[0] * inv, a[1] * inv, a[2] * inv, a[3] * inv);
        float4 o1 = make_float4(a[4] * inv, a[5] * inv, a[6] * inv, a[7] * inv);
        *(float4*)(out + ((size_t)node << 5) + (dq << 3)) = o0;
        *(float4*)(out + ((size_t)node << 5) + (dq << 3) + 4) = o1;
    }
}

extern "C" void kernel_launch(void* const* d_in, const int* in_sizes, int n_in,
                              void* d_out, int out_size, void* d_ws, size_t ws_size,
                              hipStream_t stream) {
    const void* ei = d_in[0];
    const float* ew = (const float*)d_in[1];
    const float* emb = (const float*)d_in[2];
    const float* W1 = (const float*)d_in[3];
    const float* b1 = (const float*)d_in[4];
    const float* W2 = (const float*)d_in[5];
    const float* b2 = (const float*)d_in[6];
    float* outp = (float*)d_out;

    int E = in_sizes[0] / 2;
    int N = in_sizes[2] / 64;
    int B = (N + BWIDTH - 1) >> BSHIFT;
    int GP = (E + CHUNK - 1) / CHUNK;

    char* p = (char*)d_ws;
    auto alloc = [&](size_t bytes) {
        void* q = (void*)p;
        p += (bytes + 255) & ~(size_t)255;
        return q;
    };
    unsigned int* gcnt   = (unsigned int*)alloc(256 * 4);
    unsigned int* bstart = (unsigned int*)alloc(257 * 4);
    int*          flag   = (int*)alloc(256);
    unsigned int* table  = (unsigned int*)alloc((size_t)GP * 256 * 4);
    int2*   bucketed = (int2*)alloc((size_t)E * 8);
    unsigned int* csrp = (unsigned int*)alloc(((size_t)E + 64) * 4);
    float*  dinv     = (float*)alloc((size_t)N * 4);
    int*    colptr   = (int*)alloc(((size_t)N + 1) * 4);
    __half* X1h      = (__half*)alloc((size_t)N * 64 * 2);   // reused as X2h [N][32]
    __half* H        = (__half*)alloc((size_t)N * 64 * 2);
    __half* X2h      = X1h;

    int tiles1 = (N + G1ROWS - 1) / G1ROWS;
    int tiles2 = (N + G2ROWS - 1) / G2ROWS;

    init_kernel<<<1, 256, 0, stream>>>((const int*)ei, flag, gcnt);
    p1_count_kernel<<<GP, THREADS, 0, stream>>>(ei, flag, gcnt, table, E, B);
    p2_scan_kernel<<<1, 256, 0, stream>>>(gcnt, bstart, B, E);
    p3_scatter_kernel<<<GP, THREADS, 0, stream>>>(ei, ew, flag, bstart, table,
                                                  bucketed, E, B);
    p5_bucket_kernel<<<B, P5THREADS, 0, stream>>>(bucketed, bstart, dinv, colptr, csrp, N, E);
    gemm1_kernel<<<1024, THREADS, 0, stream>>>(emb, W1, dinv, X1h, N, tiles1);
    agg1_kernel<<<(N + 3) / 4, THREADS, 0, stream>>>(X1h, colptr, csrp, dinv, b1, H, N);
    gemm2_kernel<<<1024, THREADS, 0, stream>>>(H, W2, dinv, X2h, N, tiles2);
    agg2_kernel<<<(N + 3) / 4, THREADS, 0, stream>>>(X2h, colptr, csrp, dinv, b2, outp, N);
}